// Round 3
// baseline (442.465 us; speedup 1.0000x reference)
//
#include <hip/hip_runtime.h>
#include <hip/hip_bf16.h>

#define BN    4
#define NN    2048
#define INF   128
#define HH    8
#define HD    16
#define ALPHA 0.2f
#define DECAY 0.1f

#define TI 16    // i rows per block
#define TJ 128   // j chunk staged in LDS
#define SL 4     // j slices (parallel partial softmax)

__device__ __forceinline__ float bf2f(unsigned short u) {
    return __uint_as_float(((unsigned)u) << 16);
}

// ---------------- Kernel 0: input dtype detection --------------------------
// Reads first 128 values of x and tm interpreted as bf16. Genuine bf16 data
// is bounded; fp32 data read as bf16 puts mantissa bits in the exponent field
// (huge garbage ~50% per low-half word). flag=1 -> bf16, flag=0 -> fp32.
// (Round-2 evidence: this selected fp32 and the fp32 compute path was correct.)
__global__ void k_detect(const unsigned short* __restrict__ x,
                         const unsigned short* __restrict__ tm,
                         unsigned* __restrict__ flag) {
    int t = threadIdx.x;  // 256
    bool ok;
    if (t < 128) {
        float v = bf2f(x[t]);
        ok = (v == v) && fabsf(v) <= 64.f;
    } else {
        float v = bf2f(tm[t - 128]);
        ok = (v == v) && v >= 0.f && v <= 1.f;
    }
    __shared__ int oks[256];
    oks[t] = ok ? 1 : 0;
    __syncthreads();
    if (t == 0) {
        int all = 1;
        for (int i = 0; i < 256; i++) all &= oks[i];
        flag[0] = (unsigned)all;
    }
}

// ---------------- Kernel 1: global max over time_matrix (>=0) --------------
__global__ void k_max(const void* __restrict__ tmv,
                      const unsigned* __restrict__ flag,
                      unsigned* __restrict__ ct) {
    bool isbf = flag[0] != 0u;
    int idx = blockIdx.x * blockDim.x + threadIdx.x;
    int stride = gridDim.x * blockDim.x;
    unsigned m = 0u;  // fp32 bit pattern; bit-compare == float-compare for >=0
    const uint4* p = (const uint4*)tmv;
    if (isbf) {
        const int nvec = BN * NN * NN / 8;
        for (int i = idx; i < nvec; i += stride) {
            uint4 v = p[i];
            m = max(m, v.x << 16); m = max(m, v.x & 0xffff0000u);
            m = max(m, v.y << 16); m = max(m, v.y & 0xffff0000u);
            m = max(m, v.z << 16); m = max(m, v.z & 0xffff0000u);
            m = max(m, v.w << 16); m = max(m, v.w & 0xffff0000u);
        }
    } else {
        const int nvec = BN * NN * NN / 4;
        for (int i = idx; i < nvec; i += stride) {
            uint4 v = p[i];
            m = max(m, v.x); m = max(m, v.y); m = max(m, v.z); m = max(m, v.w);
        }
    }
    float fm = __uint_as_float(m);
    #pragma unroll
    for (int o = 32; o >= 1; o >>= 1) fm = fmaxf(fm, __shfl_xor(fm, o));
    __shared__ float sm[4];
    if ((threadIdx.x & 63) == 0) sm[threadIdx.x >> 6] = fm;
    __syncthreads();
    if (threadIdx.x == 0) {
        float mm = fmaxf(fmaxf(sm[0], sm[1]), fmaxf(sm[2], sm[3]));
        atomicMax(ct, __float_as_uint(mm));
    }
}

// ---------------- Kernel 2: h = x*W ; es = h.a_src ; ed = h.a_dst ----------
__global__ void k_proj(const void* __restrict__ xv,
                       const void* __restrict__ Wv,
                       const void* __restrict__ av,
                       const unsigned* __restrict__ flag,
                       float* __restrict__ hbuf,
                       float* __restrict__ es, float* __restrict__ ed) {
    bool isbf = flag[0] != 0u;
    int b = blockIdx.x >> 11;
    int n = blockIdx.x & 2047;
    int t = threadIdx.x;  // 128 threads
    __shared__ float xs[INF];
    size_t xoff = ((size_t)(b * NN + n)) * INF + t;
    xs[t] = isbf ? bf2f(((const unsigned short*)xv)[xoff]) : ((const float*)xv)[xoff];
    __syncthreads();
    int h = t >> 4, d = t & 15;
    float acc = 0.f;
    if (isbf) {
        const unsigned short* Wp = (const unsigned short*)Wv + (h * INF) * HD + d;
        #pragma unroll 16
        for (int i = 0; i < INF; i++) acc += xs[i] * bf2f(Wp[i * HD]);
    } else {
        const float* Wp = (const float*)Wv + (h * INF) * HD + d;
        #pragma unroll 16
        for (int i = 0; i < INF; i++) acc += xs[i] * Wp[i * HD];
    }
    hbuf[((size_t)((b * HH + h) * NN + n)) * HD + d] = acc;
    float asrc, adst;
    if (isbf) {
        asrc = bf2f(((const unsigned short*)av)[h * 2 * HD + d]);
        adst = bf2f(((const unsigned short*)av)[h * 2 * HD + HD + d]);
    } else {
        asrc = ((const float*)av)[h * 2 * HD + d];
        adst = ((const float*)av)[h * 2 * HD + HD + d];
    }
    float s  = acc * asrc;
    float dd = acc * adst;
    #pragma unroll
    for (int o = 8; o >= 1; o >>= 1) { s += __shfl_xor(s, o); dd += __shfl_xor(dd, o); }
    if (d == 0) {
        es[(b * HH + h) * NN + n] = s;
        ed[(b * HH + h) * NN + n] = dd;
    }
}

// ---------------- Kernel 3: fused masked time-softmax + PV -----------------
// block: 512 threads = (js:4, h:8, il:16); grid: B * (N/TI) = 512 blocks
__launch_bounds__(512, 4)
__global__ void k_attn(const int* __restrict__ adj,
                       const void* __restrict__ tmv,
                       const float* __restrict__ hbuf,
                       const float* __restrict__ es, const float* __restrict__ ed,
                       const unsigned* __restrict__ ctp,
                       const unsigned* __restrict__ flag,
                       float* __restrict__ out) {
    bool isbf = flag[0] != 0u;
    int t  = threadIdx.x;
    int b  = blockIdx.x >> 7;              // 128 i-tiles per batch
    int i0 = (blockIdx.x & 127) * TI;
    int js = t >> 7;
    int h  = (t >> 4) & 7;
    int il = t & 15;
    int i  = i0 + il;

    // union LDS: stage region (tw 16x129 + ed 8x129 = 3096 floats)
    //            reduce region (256*17 = 4352 floats)
    __shared__ float smem[256 * 17];
    float* tw_s = smem;               // [TI][TJ+1] pad -> conflict-free col reads
    float* ed_s = smem + TI * (TJ + 1);

    float ct   = __uint_as_float(*ctp);
    float es_i = es[(b * HH + h) * NN + i];
    const float* hb = hbuf + (size_t)((b * HH + h) * NN) * HD;
    const int* adjrow = adj + (size_t)b * NN * NN + (size_t)i0 * NN;
    const unsigned short* tmrow16 = (const unsigned short*)tmv + (size_t)b * NN * NN + (size_t)i0 * NN;
    const float*          tmrow32 = (const float*)tmv          + (size_t)b * NN * NN + (size_t)i0 * NN;

    float l = 0.f;
    float acc[16];
    #pragma unroll
    for (int d = 0; d < 16; d++) acc[d] = 0.f;

    for (int j0 = 0; j0 < NN; j0 += TJ) {
        __syncthreads();
        // stage tw for TI x TJ entries: adj==0 -> mask (-1), else exp(-decay*(ct-t))
        #pragma unroll
        for (int k = 0; k < (TI * TJ) / 512; k++) {
            int e = k * 512 + t;
            int r = e >> 7, c = e & 127;
            size_t off = (size_t)r * NN + j0 + c;
            int   aj = adjrow[off];
            float tv = isbf ? bf2f(tmrow16[off]) : tmrow32[off];
            tw_s[r * (TJ + 1) + c] = (aj != 0) ? __expf(-DECAY * (ct - tv)) : -1.f;
        }
        // stage ed chunk for all heads
        #pragma unroll
        for (int k = 0; k < (HH * TJ) / 512; k++) {
            int e = k * 512 + t;
            int r = e >> 7, c = e & 127;
            ed_s[r * (TJ + 1) + c] = ed[(b * HH + r) * NN + j0 + c];
        }
        __syncthreads();

        for (int jj = js; jj < TJ; jj += SL) {
            float w  = tw_s[il * (TJ + 1) + jj];
            float s0 = es_i + ed_s[h * (TJ + 1) + jj];
            float s  = fmaxf(s0, ALPHA * s0);         // leaky_relu (alpha<1)
            float p  = (w > 0.f) ? __expf(s * w) : 0.f;
            l += p;
            const float4* hp = (const float4*)(hb + (size_t)(j0 + jj) * HD);
            float4 h0 = hp[0], h1 = hp[1], h2 = hp[2], h3 = hp[3];
            acc[0]  += p * h0.x; acc[1]  += p * h0.y; acc[2]  += p * h0.z; acc[3]  += p * h0.w;
            acc[4]  += p * h1.x; acc[5]  += p * h1.y; acc[6]  += p * h1.z; acc[7]  += p * h1.w;
            acc[8]  += p * h2.x; acc[9]  += p * h2.y; acc[10] += p * h2.z; acc[11] += p * h2.w;
            acc[12] += p * h3.x; acc[13] += p * h3.y; acc[14] += p * h3.z; acc[15] += p * h3.w;
        }
    }

    // merge the 4 j-slices (pure addition: no online max used)
    __syncthreads();
    for (int s = 2; s >= 1; s >>= 1) {
        if (js >= s && js < 2 * s) {
            int slot = t - s * 128;
            smem[slot * 17 + 16] = l;
            #pragma unroll
            for (int d = 0; d < 16; d++) smem[slot * 17 + d] = acc[d];
        }
        __syncthreads();
        if (js < s) {
            l += smem[t * 17 + 16];
            #pragma unroll
            for (int d = 0; d < 16; d++) acc[d] += smem[t * 17 + d];
        }
        __syncthreads();
    }

    if (js == 0) {
        float inv = 1.f / l;
        float* op = out + (size_t)(b * NN + i) * (HH * HD) + h * HD;
        #pragma unroll
        for (int d = 0; d < 16; d++) {
            float v = acc[d] * inv;
            v = (v > 0.f) ? v : expm1f(v);            // ELU(alpha=1)
            op[d] = v;                                 // fp32 output
        }
    }
}

extern "C" void kernel_launch(void* const* d_in, const int* in_sizes, int n_in,
                              void* d_out, int out_size, void* d_ws, size_t ws_size,
                              hipStream_t stream) {
    const void* x   = d_in[0];            // node_features (fp32; bf16 tolerated)
    const int*  adj = (const int*)d_in[1];// adjacency int32
    const void* tm  = d_in[2];            // time_matrix (fp32; bf16 tolerated)
    const void* W   = d_in[3];            // W
    const void* a   = d_in[4];            // a
    float* out = (float*)d_out;           // fp32 output (per reference dtype)

    float* wsf   = (float*)d_ws;
    unsigned* ct   = (unsigned*)wsf;               // [0]
    unsigned* flag = (unsigned*)wsf + 1;           // [1]
    float* hbuf = wsf + 64;                        // B*H*N*HD = 1,048,576 floats
    float* es   = hbuf + BN * HH * NN * HD;        // 65,536 floats
    float* ed   = es + BN * HH * NN;               // 65,536 floats

    hipMemsetAsync(d_ws, 0, 8, stream);            // ct = 0.0f, flag = 0
    k_detect<<<1, 256, 0, stream>>>((const unsigned short*)x, (const unsigned short*)tm, flag);
    k_max<<<1024, 256, 0, stream>>>(tm, flag, ct);
    k_proj<<<BN * NN, 128, 0, stream>>>(x, W, a, flag, hbuf, es, ed);
    k_attn<<<BN * (NN / TI), 512, 0, stream>>>(adj, tm, hbuf, es, ed, ct, flag, out);
}

// Round 4
// 323.061 us; speedup vs baseline: 1.3696x; 1.3696x over previous
//
#include <hip/hip_runtime.h>
#include <hip/hip_bf16.h>

#define BN    4
#define NN    2048
#define INF   128
#define HH    8
#define HD    16
#define ALPHA 0.2f
#define DECAY 0.1f

typedef __attribute__((ext_vector_type(8))) short short8;
typedef __attribute__((ext_vector_type(4))) float float4v;

__device__ __forceinline__ float bf2f(unsigned short u) {
    return __uint_as_float(((unsigned)u) << 16);
}

// ---------------- Kernel 1: ct = max(time_matrix) (fp32, values >= 0) ------
__global__ void k_max(const float* __restrict__ tm, unsigned* __restrict__ ct) {
    const uint4* p = (const uint4*)tm;
    const int nvec = BN * NN * NN / 4;  // 4,194,304
    int idx = blockIdx.x * blockDim.x + threadIdx.x;
    int stride = gridDim.x * blockDim.x;
    unsigned m = 0u;  // bit-compare == float-compare for non-negative floats
    for (int i = idx; i < nvec; i += stride) {
        uint4 v = p[i];
        m = max(m, v.x); m = max(m, v.y); m = max(m, v.z); m = max(m, v.w);
    }
    float fm = __uint_as_float(m);
    #pragma unroll
    for (int o = 32; o >= 1; o >>= 1) fm = fmaxf(fm, __shfl_xor(fm, o));
    __shared__ float sm[4];
    if ((threadIdx.x & 63) == 0) sm[threadIdx.x >> 6] = fm;
    __syncthreads();
    if (threadIdx.x == 0) {
        float mm = fmaxf(fmaxf(sm[0], sm[1]), fmaxf(sm[2], sm[3]));
        atomicMax(ct, __float_as_uint(mm));
    }
}

// ---------------- Kernel 2: h_t (bf16, transposed) ; es ; ed ---------------
// h_t[b,h,d,n] so k_attn's B-fragment is one contiguous 16-byte load.
__global__ void k_proj(const float* __restrict__ x,
                       const float* __restrict__ W,
                       const float* __restrict__ a,
                       __hip_bfloat16* __restrict__ h_t,
                       float* __restrict__ es, float* __restrict__ ed) {
    int b = blockIdx.x >> 11;
    int n = blockIdx.x & 2047;
    int t = threadIdx.x;  // 128 threads
    __shared__ float xs[INF];
    xs[t] = x[((size_t)(b * NN + n)) * INF + t];
    __syncthreads();
    int h = t >> 4, d = t & 15;
    const float* Wp = W + (h * INF) * HD + d;
    float acc = 0.f;
    #pragma unroll 16
    for (int i = 0; i < INF; i++) acc += xs[i] * Wp[i * HD];
    h_t[((size_t)((b * HH + h) * HD + d)) * NN + n] = __float2bfloat16(acc);
    float s  = acc * a[h * 2 * HD + d];
    float dd = acc * a[h * 2 * HD + HD + d];
    #pragma unroll
    for (int o = 8; o >= 1; o >>= 1) { s += __shfl_xor(s, o); dd += __shfl_xor(dd, o); }
    if (d == 0) {
        es[(b * HH + h) * NN + n] = s;
        ed[(b * HH + h) * NN + n] = dd;
    }
}

// ---------------- Kernel 3: fused scores + softmax + PV via MFMA -----------
// grid: B * (N/16) = 512 blocks; block: 512 threads = 8 waves, wave = head.
// Per 16x32 MFMA step each lane computes 8 scores (i = lane&15,
// j = jc + quad*8 + k), packs them as the bf16 A-fragment, and the
// B-fragment h_t[b,h,d=lane&15, jc+quad*8 .. +7] is ONE dwordx4 load.
// No LDS, no __syncthreads in the loop.
__launch_bounds__(512, 4)
__global__ void k_attn(const int* __restrict__ adj,
                       const float* __restrict__ tm,
                       const __hip_bfloat16* __restrict__ h_t,
                       const float* __restrict__ es, const float* __restrict__ ed,
                       const unsigned* __restrict__ ctp,
                       float* __restrict__ out) {
    int t    = threadIdx.x;
    int w    = t >> 6;          // head
    int lane = t & 63;
    int q    = lane >> 4;       // quad 0..3
    int im   = lane & 15;       // i within tile / d for B-frag
    int b    = blockIdx.x >> 7;
    int i0   = (blockIdx.x & 127) << 4;
    int i    = i0 + im;

    float negdct = -DECAY * __uint_as_float(*ctp);
    float es_i = es[(b * HH + w) * NN + i];

    const float* tm_p  = tm  + ((size_t)(b * NN + i)) * NN + q * 8;
    const int*   adj_p = adj + ((size_t)(b * NN + i)) * NN + q * 8;
    const float* ed_p  = ed  + (size_t)(b * HH + w) * NN + q * 8;
    const __hip_bfloat16* ht_p = h_t + ((size_t)((b * HH + w) * HD + im)) * NN + q * 8;

    float4v acc = {0.f, 0.f, 0.f, 0.f};
    float lsum = 0.f;

    for (int jc = 0; jc < NN; jc += 32) {
        float4 t0 = *(const float4*)(tm_p + jc);
        float4 t1 = *(const float4*)(tm_p + jc + 4);
        int4   a0 = *(const int4*)(adj_p + jc);
        int4   a1 = *(const int4*)(adj_p + jc + 4);
        float4 e0 = *(const float4*)(ed_p + jc);
        float4 e1 = *(const float4*)(ed_p + jc + 4);
        uint4  hv = *(const uint4*)(ht_p + jc);

        float tv[8] = {t0.x, t0.y, t0.z, t0.w, t1.x, t1.y, t1.z, t1.w};
        int   av[8] = {a0.x, a0.y, a0.z, a0.w, a1.x, a1.y, a1.z, a1.w};
        float ev[8] = {e0.x, e0.y, e0.z, e0.w, e1.x, e1.y, e1.z, e1.w};

        union { unsigned short us[8]; short8 v; } af;
        #pragma unroll
        for (int k = 0; k < 8; k++) {
            float tw  = __expf(fmaf(DECAY, tv[k], negdct));   // exp(-d*(ct-t))
            float s0  = es_i + ev[k];
            float s   = fmaxf(s0, ALPHA * s0);                // leaky_relu
            float arg = s * tw;
            arg = (av[k] != 0) ? arg : -__builtin_inff();     // mask -> p = 0
            float pv = __expf(arg);
            __hip_bfloat16 hb = __float2bfloat16(pv);         // RTNE
            unsigned short ub;
            __builtin_memcpy(&ub, &hb, 2);
            af.us[k] = ub;
            lsum += bf2f(ub);   // denominator from the SAME rounded p
        }
        union { uint4 u; short8 v; } bf;
        bf.u = hv;
        acc = __builtin_amdgcn_mfma_f32_16x16x32_bf16(af.v, bf.v, acc, 0, 0, 0);
    }

    // full row-sum l(i): partials live on lanes {i, i+16, i+32, i+48}
    lsum += __shfl_xor(lsum, 16);
    lsum += __shfl_xor(lsum, 32);
    float inv = 1.f / lsum;     // lane holds inv for row i = im

    // D layout (m89-verified): col = lane&15, row = quad*4 + reg
    #pragma unroll
    for (int r = 0; r < 4; r++) {
        int row = q * 4 + r;
        float invr = __shfl(inv, row);          // lane 'row' holds l(row)
        float v = acc[r] * invr;
        v = (v > 0.f) ? v : expm1f(v);          // ELU
        out[((size_t)(b * NN + i0 + row)) * (HH * HD) + w * HD + im] = v;
    }
}

extern "C" void kernel_launch(void* const* d_in, const int* in_sizes, int n_in,
                              void* d_out, int out_size, void* d_ws, size_t ws_size,
                              hipStream_t stream) {
    const float* x   = (const float*)d_in[0];  // node_features fp32
    const int*   adj = (const int*)d_in[1];    // adjacency int32
    const float* tm  = (const float*)d_in[2];  // time_matrix fp32
    const float* W   = (const float*)d_in[3];  // W fp32
    const float* a   = (const float*)d_in[4];  // a fp32
    float* out = (float*)d_out;                // fp32 output

    float* wsf = (float*)d_ws;
    unsigned* ct = (unsigned*)wsf;                       // [0]
    float* es = wsf + 64;                                // 65,536 floats
    float* ed = es + BN * HH * NN;                       // 65,536 floats
    __hip_bfloat16* h_t = (__hip_bfloat16*)(ed + BN * HH * NN);  // 1,048,576 bf16

    hipMemsetAsync(d_ws, 0, 4, stream);                  // ct = 0.0f (t >= 0)
    k_max <<<1024, 256, 0, stream>>>(tm, ct);
    k_proj<<<BN * NN, 128, 0, stream>>>(x, W, a, h_t, es, ed);
    k_attn<<<BN * (NN / 16), 512, 0, stream>>>(adj, tm, h_t, es, ed, ct, out);
}

// Round 5
// 235.344 us; speedup vs baseline: 1.8801x; 1.3727x over previous
//
#include <hip/hip_runtime.h>
#include <hip/hip_bf16.h>

#define BN    4
#define NN    2048
#define INF   128
#define HH    8
#define HD    16
#define ALPHA 0.2f
#define DECAY 0.1f

typedef __attribute__((ext_vector_type(8))) short short8;
typedef __attribute__((ext_vector_type(4))) float float4v;

__device__ __forceinline__ float bf2f(unsigned short u) {
    return __uint_as_float(((unsigned)u) << 16);
}

// ---------------- Kernel 1: ct = max(time_matrix) (fp32, values >= 0) ------
__global__ void k_max(const float* __restrict__ tm, unsigned* __restrict__ ct) {
    const uint4* p = (const uint4*)tm;
    const int nvec = BN * NN * NN / 4;  // 4,194,304
    int idx = blockIdx.x * blockDim.x + threadIdx.x;
    int stride = gridDim.x * blockDim.x;
    unsigned m = 0u;  // bit-compare == float-compare for non-negative floats
    for (int i = idx; i < nvec; i += stride) {
        uint4 v = p[i];
        m = max(m, v.x); m = max(m, v.y); m = max(m, v.z); m = max(m, v.w);
    }
    float fm = __uint_as_float(m);
    #pragma unroll
    for (int o = 32; o >= 1; o >>= 1) fm = fmaxf(fm, __shfl_xor(fm, o));
    __shared__ float sm[4];
    if ((threadIdx.x & 63) == 0) sm[threadIdx.x >> 6] = fm;
    __syncthreads();
    if (threadIdx.x == 0) {
        float mm = fmaxf(fmaxf(sm[0], sm[1]), fmaxf(sm[2], sm[3]));
        atomicMax(ct, __float_as_uint(mm));
    }
}

// ---------------- Kernel 2: h_t (bf16, transposed) ; es ; ed ---------------
// h_t[b,h,d,n] so k_attn's B-fragment is one contiguous 16-byte load.
__global__ void k_proj(const float* __restrict__ x,
                       const float* __restrict__ W,
                       const float* __restrict__ a,
                       __hip_bfloat16* __restrict__ h_t,
                       float* __restrict__ es, float* __restrict__ ed) {
    int b = blockIdx.x >> 11;
    int n = blockIdx.x & 2047;
    int t = threadIdx.x;  // 128 threads
    __shared__ float xs[INF];
    xs[t] = x[((size_t)(b * NN + n)) * INF + t];
    __syncthreads();
    int h = t >> 4, d = t & 15;
    const float* Wp = W + (h * INF) * HD + d;
    float acc = 0.f;
    #pragma unroll 16
    for (int i = 0; i < INF; i++) acc += xs[i] * Wp[i * HD];
    h_t[((size_t)((b * HH + h) * HD + d)) * NN + n] = __float2bfloat16(acc);
    float s  = acc * a[h * 2 * HD + d];
    float dd = acc * a[h * 2 * HD + HD + d];
    #pragma unroll
    for (int o = 8; o >= 1; o >>= 1) { s += __shfl_xor(s, o); dd += __shfl_xor(dd, o); }
    if (d == 0) {
        es[(b * HH + h) * NN + n] = s;
        ed[(b * HH + h) * NN + n] = dd;
    }
}

// ---------------- Kernel 3: fused scores + softmax + PV via MFMA -----------
// grid: B * (N/16) = 512 blocks; block: 512 threads = 8 waves, wave = head.
// Per 128-j round, the block cooperatively stages the HEAD-INDEPENDENT
// masked time-weight w(i,j) = adj ? exp(-d*(ct-t)) : 0 into LDS ONCE
// (register-prefetched one round ahead), killing the 8x per-head redundancy
// in exp + tm/adj loads that made Round 4 latency-bound.
__launch_bounds__(512, 4)
__global__ void k_attn(const int* __restrict__ adj,
                       const float* __restrict__ tm,
                       const __hip_bfloat16* __restrict__ h_t,
                       const float* __restrict__ es, const float* __restrict__ ed,
                       const unsigned* __restrict__ ctp,
                       float* __restrict__ out) {
    int t    = threadIdx.x;
    int w    = t >> 6;          // head
    int lane = t & 63;
    int q    = lane >> 4;       // quad 0..3
    int im   = lane & 15;       // i within tile / d for B-frag
    int b    = blockIdx.x >> 7;
    int i0   = (blockIdx.x & 127) << 4;
    int i    = i0 + im;

    // tw tile: 16 rows x 128 j, stride 132 (16B-aligned rows, low conflicts)
    __shared__ float tws[16][132];

    float negdct = -DECAY * __uint_as_float(*ctp);
    float es_i = es[(b * HH + w) * NN + i];

    const float* ed_p = ed + (size_t)(b * HH + w) * NN + q * 8;
    const __hip_bfloat16* ht_p = h_t + ((size_t)((b * HH + w) * HD + im)) * NN + q * 8;

    // staging map: 512 threads x 4 elements = 16 rows x 128 cols
    int srow = t >> 5;            // 0..15
    int scol = (t & 31) << 2;     // 0,4,...,124
    const int*   adj_s = adj + ((size_t)(b * NN + i0 + srow)) * NN + scol;
    const float* tm_s  = tm  + ((size_t)(b * NN + i0 + srow)) * NN + scol;

    float4v acc = {0.f, 0.f, 0.f, 0.f};
    float lsum = 0.f;

    // prefetch round 0
    int4   pa = *(const int4*)(adj_s);
    float4 pt = *(const float4*)(tm_s);

    for (int r = 0; r < 16; r++) {
        // compute w' for the 4 prefetched elements
        float w0 = (pa.x != 0) ? __expf(fmaf(DECAY, pt.x, negdct)) : 0.f;
        float w1 = (pa.y != 0) ? __expf(fmaf(DECAY, pt.y, negdct)) : 0.f;
        float w2 = (pa.z != 0) ? __expf(fmaf(DECAY, pt.z, negdct)) : 0.f;
        float w3 = (pa.w != 0) ? __expf(fmaf(DECAY, pt.w, negdct)) : 0.f;

        __syncthreads();   // previous round's LDS fully consumed
        *(float4*)&tws[srow][scol] = make_float4(w0, w1, w2, w3);

        // issue next round's staging loads NOW (covered by this round's compute)
        if (r + 1 < 16) {
            pa = *(const int4*)(adj_s + (r + 1) * 128);
            pt = *(const float4*)(tm_s + (r + 1) * 128);
        }
        __syncthreads();   // tile visible to all waves

        #pragma unroll
        for (int c4 = 0; c4 < 4; c4++) {
            int jl = c4 * 32 + q * 8;        // within-round col for this lane
            int jglob = r * 128 + c4 * 32;   // chunk base (q*8 already in ptrs)

            float4 w01 = *(const float4*)&tws[im][jl];
            float4 w23 = *(const float4*)&tws[im][jl + 4];
            float4 e0 = *(const float4*)(ed_p + jglob);
            float4 e1 = *(const float4*)(ed_p + jglob + 4);
            uint4  hv = *(const uint4*)(ht_p + jglob);

            float wv[8] = {w01.x, w01.y, w01.z, w01.w, w23.x, w23.y, w23.z, w23.w};
            float ev[8] = {e0.x, e0.y, e0.z, e0.w, e1.x, e1.y, e1.z, e1.w};

            union { unsigned short us[8]; short8 v; } af;
            #pragma unroll
            for (int k = 0; k < 8; k++) {
                float s0  = es_i + ev[k];
                float sc  = fmaxf(s0, ALPHA * s0);          // leaky_relu
                float pv  = __expf(sc * wv[k]);
                pv = (wv[k] > 0.f) ? pv : 0.f;              // masked -> 0
                __hip_bfloat16 hb = __float2bfloat16(pv);   // RTNE
                unsigned short ub;
                __builtin_memcpy(&ub, &hb, 2);
                af.us[k] = ub;
                lsum += bf2f(ub);   // denominator from the SAME rounded p
            }
            union { uint4 u; short8 v; } bf;
            bf.u = hv;
            acc = __builtin_amdgcn_mfma_f32_16x16x32_bf16(af.v, bf.v, acc, 0, 0, 0);
        }
    }

    // full row-sum l(i): partials live on lanes {i, i+16, i+32, i+48}
    lsum += __shfl_xor(lsum, 16);
    lsum += __shfl_xor(lsum, 32);
    float inv = 1.f / lsum;     // lane holds inv for row i = im

    // D layout (m89-verified): col = lane&15, row = quad*4 + reg
    #pragma unroll
    for (int r = 0; r < 4; r++) {
        int row = q * 4 + r;
        float invr = __shfl(inv, row);          // lane 'row' holds l(row)
        float v = acc[r] * invr;
        v = (v > 0.f) ? v : expm1f(v);          // ELU
        out[((size_t)(b * NN + i0 + row)) * (HH * HD) + w * HD + im] = v;
    }
}

extern "C" void kernel_launch(void* const* d_in, const int* in_sizes, int n_in,
                              void* d_out, int out_size, void* d_ws, size_t ws_size,
                              hipStream_t stream) {
    const float* x   = (const float*)d_in[0];  // node_features fp32
    const int*   adj = (const int*)d_in[1];    // adjacency int32
    const float* tm  = (const float*)d_in[2];  // time_matrix fp32
    const float* W   = (const float*)d_in[3];  // W fp32
    const float* a   = (const float*)d_in[4];  // a fp32
    float* out = (float*)d_out;                // fp32 output

    float* wsf = (float*)d_ws;
    unsigned* ct = (unsigned*)wsf;                       // [0]
    float* es = wsf + 64;                                // 65,536 floats
    float* ed = es + BN * HH * NN;                       // 65,536 floats
    __hip_bfloat16* h_t = (__hip_bfloat16*)(ed + BN * HH * NN);  // 1,048,576 bf16

    hipMemsetAsync(d_ws, 0, 4, stream);                  // ct = 0.0f (t >= 0)
    k_max <<<1024, 256, 0, stream>>>(tm, ct);
    k_proj<<<BN * NN, 128, 0, stream>>>(x, W, a, h_t, es, ed);
    k_attn<<<BN * (NN / 16), 512, 0, stream>>>(adj, tm, h_t, es, ed, ct, out);
}

// Round 6
// 234.140 us; speedup vs baseline: 1.8897x; 1.0051x over previous
//
#include <hip/hip_runtime.h>
#include <hip/hip_bf16.h>

#define BN    4
#define NN    2048
#define INF   128
#define HH    8
#define HD    16
#define ALPHA 0.2f
#define DECAY 0.1f

// exp2 folding constants: w2 = log2e * exp(-DECAY*(ct - t)) computed as
// exp2(fma(DECAY*log2e, t, -DECAY*log2e*ct + log2(log2e)))
#define DLOG2E 0.14426950408889634f   // DECAY * log2(e)
#define LLOG2E 0.5287663729448977f    // log2(log2(e))

typedef __attribute__((ext_vector_type(8))) short short8;
typedef __attribute__((ext_vector_type(4))) float float4v;

__device__ __forceinline__ float bf2f(unsigned short u) {
    return __uint_as_float(((unsigned)u) << 16);
}

// ---------------- Kernel 1: fused [max over tm] + [proj h_t/es/ed] ---------
// blocks 0..1023: grid-stride max reduction (HBM-bound).
// blocks 1024..5119: projection, 2 nodes per block (latency-bound; overlaps).
__launch_bounds__(256, 8)
__global__ void k_setup(const float* __restrict__ x,
                        const float* __restrict__ W,
                        const float* __restrict__ a,
                        const float* __restrict__ tm,
                        unsigned* __restrict__ ct,
                        __hip_bfloat16* __restrict__ h_t,
                        float* __restrict__ es, float* __restrict__ ed) {
    if (blockIdx.x < 1024) {
        // ---- role A: ct = max(tm), values >= 0 so u32-compare == f32-compare
        const uint4* p = (const uint4*)tm;
        const int nvec = BN * NN * NN / 4;  // 4,194,304
        int idx = blockIdx.x * 256 + threadIdx.x;
        const int stride = 1024 * 256;
        unsigned m = 0u;
        for (int i = idx; i < nvec; i += stride) {
            uint4 v = p[i];
            m = max(m, v.x); m = max(m, v.y); m = max(m, v.z); m = max(m, v.w);
        }
        float fm = __uint_as_float(m);
        #pragma unroll
        for (int o = 32; o >= 1; o >>= 1) fm = fmaxf(fm, __shfl_xor(fm, o));
        __shared__ float sm[4];
        if ((threadIdx.x & 63) == 0) sm[threadIdx.x >> 6] = fm;
        __syncthreads();
        if (threadIdx.x == 0) {
            float mm = fmaxf(fmaxf(sm[0], sm[1]), fmaxf(sm[2], sm[3]));
            atomicMax(ct, __float_as_uint(mm));
        }
    } else {
        // ---- role B: h = x W ; h_t (bf16 transposed) ; es ; ed
        int bid = blockIdx.x - 1024;          // 0..4095
        int sub = threadIdx.x >> 7;           // which of 2 nodes
        int tt  = threadIdx.x & 127;
        int nn  = bid * 2 + sub;              // global node 0..8191 (= b*NN+n)
        __shared__ float xs[2][INF];
        xs[sub][tt] = x[(size_t)nn * INF + tt];
        __syncthreads();
        int h = tt >> 4, d = tt & 15;
        const float* Wp = W + (h * INF) * HD + d;
        float acc = 0.f;
        #pragma unroll 16
        for (int i = 0; i < INF; i++) acc += xs[sub][i] * Wp[i * HD];
        int b = nn >> 11, n = nn & 2047;
        h_t[((size_t)((b * HH + h) * HD + d)) * NN + n] = __float2bfloat16(acc);
        float s  = acc * a[h * 2 * HD + d];
        float dd = acc * a[h * 2 * HD + HD + d];
        #pragma unroll
        for (int o = 8; o >= 1; o >>= 1) { s += __shfl_xor(s, o); dd += __shfl_xor(dd, o); }
        if (d == 0) {
            es[(b * HH + h) * NN + n] = s;
            ed[(b * HH + h) * NN + n] = dd;
        }
    }
}

// ---------------- Kernel 2: fused scores + partial softmax + PV (MFMA) -----
// grid: B * 2(j-half) * 128(i-tile) = 1024 blocks -> 4 blocks/CU, 32 waves/CU.
// block: 512 thr = 8 waves, wave = head. Per 128-j round the block stages the
// head-independent masked w2 = log2e*exp(-d*(ct-t)) into a DOUBLE-BUFFERED
// LDS tile (one barrier per round). Partial (acc,l) written to ws; k_fin
// combines the two j-halves.
__launch_bounds__(512, 8)
__global__ void k_attn(const int* __restrict__ adj,
                       const float* __restrict__ tm,
                       const __hip_bfloat16* __restrict__ h_t,
                       const float* __restrict__ es, const float* __restrict__ ed,
                       const unsigned* __restrict__ ctp,
                       float* __restrict__ pacc, float* __restrict__ pl) {
    int t    = threadIdx.x;
    int w    = t >> 6;          // head
    int lane = t & 63;
    int q    = lane >> 4;       // quad 0..3
    int im   = lane & 15;       // i within tile / d for B-frag
    int bx   = blockIdx.x;
    int b    = bx >> 8;
    int half = (bx >> 7) & 1;
    int i0   = (bx & 127) << 4;
    int i    = i0 + im;
    int jb   = half << 10;      // j-half base: 0 or 1024
    const int R = 8;            // 8 rounds x 128 j = 1024 j

    __shared__ float tws[2][16][132];   // double buffer; stride 132 (16B align)

    float ctv = __uint_as_float(*ctp);
    float c0  = fmaf(-DLOG2E, ctv, LLOG2E);   // -D*log2e*ct + log2(log2e)
    float es_i = es[(b * HH + w) * NN + i];

    const float* ed_p = ed + (size_t)(b * HH + w) * NN + jb + q * 8;
    const __hip_bfloat16* ht_p = h_t + ((size_t)((b * HH + w) * HD + im)) * NN + jb + q * 8;

    // staging map: 512 threads x 4 elements = 16 rows x 128 cols
    int srow = t >> 5;            // 0..15
    int scol = (t & 31) << 2;     // 0,4,...,124
    const int*   adj_s = adj + ((size_t)(b * NN + i0 + srow)) * NN + jb + scol;
    const float* tm_s  = tm  + ((size_t)(b * NN + i0 + srow)) * NN + jb + scol;

    float4v acc = {0.f, 0.f, 0.f, 0.f};
    float lsum = 0.f;

    // prologue: stage round 0, prefetch round 1
    int4   pa = *(const int4*)(adj_s);
    float4 pt = *(const float4*)(tm_s);
    {
        float w0 = (pa.x != 0) ? exp2f(fmaf(DLOG2E, pt.x, c0)) : 0.f;
        float w1 = (pa.y != 0) ? exp2f(fmaf(DLOG2E, pt.y, c0)) : 0.f;
        float w2 = (pa.z != 0) ? exp2f(fmaf(DLOG2E, pt.z, c0)) : 0.f;
        float w3 = (pa.w != 0) ? exp2f(fmaf(DLOG2E, pt.w, c0)) : 0.f;
        *(float4*)&tws[0][srow][scol] = make_float4(w0, w1, w2, w3);
    }
    pa = *(const int4*)(adj_s + 128);
    pt = *(const float4*)(tm_s + 128);
    __syncthreads();

    for (int r = 0; r < R; r++) {
        int cur = r & 1;
        // stage round r+1 into the other buffer; prefetch round r+2
        if (r + 1 < R) {
            float w0 = (pa.x != 0) ? exp2f(fmaf(DLOG2E, pt.x, c0)) : 0.f;
            float w1 = (pa.y != 0) ? exp2f(fmaf(DLOG2E, pt.y, c0)) : 0.f;
            float w2 = (pa.z != 0) ? exp2f(fmaf(DLOG2E, pt.z, c0)) : 0.f;
            float w3 = (pa.w != 0) ? exp2f(fmaf(DLOG2E, pt.w, c0)) : 0.f;
            *(float4*)&tws[cur ^ 1][srow][scol] = make_float4(w0, w1, w2, w3);
            if (r + 2 < R) {
                pa = *(const int4*)(adj_s + (r + 2) * 128);
                pt = *(const float4*)(tm_s + (r + 2) * 128);
            }
        }
        // consume round r
        #pragma unroll
        for (int c4 = 0; c4 < 4; c4++) {
            int jl = c4 * 32 + q * 8;
            int jglob = r * 128 + c4 * 32;

            float4 w01 = *(const float4*)&tws[cur][im][jl];
            float4 w23 = *(const float4*)&tws[cur][im][jl + 4];
            float4 e0 = *(const float4*)(ed_p + jglob);
            float4 e1 = *(const float4*)(ed_p + jglob + 4);
            uint4  hv = *(const uint4*)(ht_p + jglob);

            float wv[8] = {w01.x, w01.y, w01.z, w01.w, w23.x, w23.y, w23.z, w23.w};
            float ev[8] = {e0.x, e0.y, e0.z, e0.w, e1.x, e1.y, e1.z, e1.w};

            union { unsigned short us[8]; short8 v; } af;
            #pragma unroll
            for (int k = 0; k < 8; k++) {
                float s0 = es_i + ev[k];
                float sc = fmaxf(s0, ALPHA * s0);     // leaky_relu
                float pv = exp2f(sc * wv[k]);         // w2 pre-scaled by log2e
                pv = (wv[k] > 0.f) ? pv : 0.f;        // masked -> 0
                lsum += pv;
                __hip_bfloat16 hb = __float2bfloat16(pv);
                unsigned short ub;
                __builtin_memcpy(&ub, &hb, 2);
                af.us[k] = ub;
            }
            union { uint4 u; short8 v; } bf;
            bf.u = hv;
            acc = __builtin_amdgcn_mfma_f32_16x16x32_bf16(af.v, bf.v, acc, 0, 0, 0);
        }
        __syncthreads();
    }

    // partial row-sum l(i): lanes {i, i+16, i+32, i+48} hold quad partials
    lsum += __shfl_xor(lsum, 16);
    lsum += __shfl_xor(lsum, 32);

    // dump partials: pacc[((bx*8+w)*16+row)*16+col], pl[bx*128+w*16+row]
    float* pb = pacc + (((size_t)bx * 8 + w) * 16) * 16;
    #pragma unroll
    for (int r = 0; r < 4; r++) {
        int row = q * 4 + r;
        pb[row * 16 + im] = acc[r];   // D layout: col=lane&15, row=q*4+reg
    }
    if (q == 0) pl[(size_t)bx * 128 + w * 16 + im] = lsum;
}

// ---------------- Kernel 3: combine j-halves + normalize + ELU -------------
__launch_bounds__(256, 8)
__global__ void k_fin(const float* __restrict__ pacc, const float* __restrict__ pl,
                      float* __restrict__ out) {
    int o = blockIdx.x * 256 + threadIdx.x;   // B*N*H*HD = 1,048,576
    int b   = o >> 18;
    int rem = o & 262143;
    int i   = rem >> 7;
    int hd  = rem & 127;
    int h   = hd >> 4;
    int d   = hd & 15;
    int it  = i >> 4;
    int row = i & 15;
    int blk0 = (b * 2 + 0) * 128 + it;
    int blk1 = blk0 + 128;
    float a0 = pacc[(((size_t)blk0 * 8 + h) * 16 + row) * 16 + d];
    float a1 = pacc[(((size_t)blk1 * 8 + h) * 16 + row) * 16 + d];
    float l  = pl[(size_t)blk0 * 128 + h * 16 + row]
             + pl[(size_t)blk1 * 128 + h * 16 + row];
    float v = (a0 + a1) / l;
    v = (v > 0.f) ? v : expm1f(v);   // ELU
    out[o] = v;
}

extern "C" void kernel_launch(void* const* d_in, const int* in_sizes, int n_in,
                              void* d_out, int out_size, void* d_ws, size_t ws_size,
                              hipStream_t stream) {
    const float* x   = (const float*)d_in[0];  // node_features fp32
    const int*   adj = (const int*)d_in[1];    // adjacency int32
    const float* tm  = (const float*)d_in[2];  // time_matrix fp32
    const float* W   = (const float*)d_in[3];  // W fp32
    const float* a   = (const float*)d_in[4];  // a fp32
    float* out = (float*)d_out;                // fp32 output

    float* wsf = (float*)d_ws;
    unsigned* ct = (unsigned*)wsf;                           // 1 word
    float* es = wsf + 64;                                    // 65,536
    float* ed = es + BN * HH * NN;                           // 65,536
    __hip_bfloat16* h_t = (__hip_bfloat16*)(ed + BN * HH * NN);  // 1,048,576 bf16
    float* pacc = (float*)(h_t + BN * HH * HD * NN);         // 2,097,152
    float* pl   = pacc + 1024 * 2048;                        // 131,072
    // total ws use ~= 11.5 MB

    hipMemsetAsync(d_ws, 0, 4, stream);                      // ct = 0.0f (t >= 0)
    k_setup<<<1024 + 4096, 256, 0, stream>>>(x, W, a, tm, ct, h_t, es, ed);
    k_attn <<<BN * 2 * (NN / 16), 512, 0, stream>>>(adj, tm, h_t, es, ed, ct, pacc, pl);
    k_fin  <<<(BN * NN * HH * HD) / 256, 256, 0, stream>>>(pacc, pl, out);
}